// Round 9
// baseline (395.917 us; speedup 1.0000x reference)
//
#include <hip/hip_runtime.h>
#include <hip/hip_bf16.h>

// TopoGraphBlock on MI355X — round 9 (= round 6/7/8 resubmit; 3x GPU timeout).
// Change under test (vs round-5's 325us baseline): T14 double-buffered edge
// staging on EPI==0 (jj, tj). Audited 3x; no defects. Prediction: jj 80 ->
// ~45-60us, total -> ~280-300us, absmax 0.015625.
//
// Round-5 evidence: total 325us; edge_mfma jj = 80us, MfmaUtil 31%,
// VALUBusy 38%, bank conflicts negligible — barrier/latency-bound on the
// stage -> barrier -> MFMA serialization (MFMA floor ~4us).
// EPI==0 pipeline: loads(g+1) -> MFMA+epilogue(g) -> vmcnt+cvt+ds_write(g+1)
// -> barrier.  LDS 26.5 -> 52.7KB (4 -> 3 blocks/CU), __launch_bounds__(512,6).
// EPI 1/2 (jt, cls) keep single-buffer (POUT LDS would cost a block/CU).
//
// Split-bf16: A*B ~= Ah*Bh + Al*Bh + Ah*Bl, Al=bf16(A-Ah), rel err ~2^-17.
// MFMA 16x16x32 bf16 layouts (HW-validated rounds 2-5):
//   A: lane holds A[row=lane&15][k=(lane>>4)*8 .. +7]
//   B: lane holds B[k=(lane>>4)*8 .. +7][col=lane&15]
//   D: lane reg j holds D[row=(lane>>4)*4+j][col=lane&15]

#define DEVI __device__ __forceinline__

typedef __attribute__((ext_vector_type(4))) float  floatx4;
typedef __attribute__((ext_vector_type(8))) __bf16 bf16x8;
typedef __attribute__((ext_vector_type(4))) __bf16 bf16x4;

DEVI float4 f4z() { return make_float4(0.f, 0.f, 0.f, 0.f); }
DEVI float4 f4fma(float a, const float4 b, float4 c) {
    c.x = fmaf(a, b.x, c.x); c.y = fmaf(a, b.y, c.y);
    c.z = fmaf(a, b.z, c.z); c.w = fmaf(a, b.w, c.w);
    return c;
}
DEVI float4 f4add(float4 a, const float4 b) {
    a.x += b.x; a.y += b.y; a.z += b.z; a.w += b.w; return a;
}
DEVI float4 f4relu(float4 a) {
    a.x = fmaxf(a.x, 0.f); a.y = fmaxf(a.y, 0.f);
    a.z = fmaxf(a.z, 0.f); a.w = fmaxf(a.w, 0.f);
    return a;
}
DEVI floatx4 mfma_bf16(bf16x8 a, bf16x8 b, floatx4 c) {
    return __builtin_amdgcn_mfma_f32_16x16x32_bf16(a, b, c, 0, 0, 0);
}

// ---------------------------------------------------------------------------
// K0: weight prep — transpose + hi/lo bf16 split.  out[N][K] from src[K][N].
// ---------------------------------------------------------------------------
struct PrepJob { const float* src; __bf16* dh; __bf16* dl; int K; int N; };
struct PrepJobs { PrepJob j[4]; };

__global__ __launch_bounds__(256) void prep_kernel(PrepJobs jobs) {
    const PrepJob jb = jobs.j[blockIdx.y];
    const int n = jb.K * jb.N;
    for (int i = blockIdx.x * 256 + threadIdx.x; i < n; i += gridDim.x * 256) {
        const int c = i / jb.K, k = i - c * jb.K;
        const float w = jb.src[(size_t)k * jb.N + c];
        const __bf16 h = (__bf16)w;
        jb.dh[i] = h;
        jb.dl[i] = (__bf16)(w - (float)h);
    }
}

// ---------------------------------------------------------------------------
// K1: batched per-node first-layer GEMM (fp32). out(nr x 128) = X(nr x 64) @ W(64 x 128)
// ---------------------------------------------------------------------------
struct PreCfg { const float* X; const float* W; const float* bias; float* out; int nrows; };
struct PreCfg6 { PreCfg c[6]; };

__global__ __launch_bounds__(256) void pre_gemm_kernel(PreCfg6 cfgs) {
    const PreCfg cfg = cfgs.c[blockIdx.y];
    if ((int)blockIdx.x * 32 >= cfg.nrows) return;
    __shared__ float Xs[32][64];
    __shared__ float Ws[64][128];
    const int tid = threadIdx.x;
    {
        const float4* s = (const float4*)(cfg.X + (size_t)blockIdx.x * 2048);
        float4* d = (float4*)&Xs[0][0];
        d[tid] = s[tid]; d[tid + 256] = s[tid + 256];
    }
    {
        const float4* s = (const float4*)cfg.W;
        float4* d = (float4*)&Ws[0][0];
        #pragma unroll
        for (int u = 0; u < 8; ++u) d[tid + u * 256] = s[tid + u * 256];
    }
    __syncthreads();
    const int cg = tid & 31, rg = tid >> 5;
    const int c0 = cg * 4, r0 = rg * 4;
    float4 acc[4] = {f4z(), f4z(), f4z(), f4z()};
    #pragma unroll 4
    for (int k = 0; k < 64; k += 4) {
        const float4 w0 = *(const float4*)&Ws[k + 0][c0];
        const float4 w1 = *(const float4*)&Ws[k + 1][c0];
        const float4 w2 = *(const float4*)&Ws[k + 2][c0];
        const float4 w3 = *(const float4*)&Ws[k + 3][c0];
        #pragma unroll
        for (int i = 0; i < 4; ++i) {
            const float4 x = *(const float4*)&Xs[r0 + i][k];
            acc[i] = f4fma(x.x, w0, acc[i]);
            acc[i] = f4fma(x.y, w1, acc[i]);
            acc[i] = f4fma(x.z, w2, acc[i]);
            acc[i] = f4fma(x.w, w3, acc[i]);
        }
    }
    const float4 bv = cfg.bias ? *(const float4*)(cfg.bias + c0) : f4z();
    #pragma unroll
    for (int i = 0; i < 4; ++i)
        *(float4*)&cfg.out[((size_t)blockIdx.x * 32 + r0 + i) * 128 + c0] = f4add(acc[i], bv);
}

// ---------------------------------------------------------------------------
// K2: edge layer-2 GEMM on MFMA, split-bf16, fused pooling epilogue.
// EPI: 0 = register pooling (jj, tj) — double-buffered T14 pipeline,
//      1 = LDS segment reduce (jt), 2 = classifier score (single-buffered).
// ---------------------------------------------------------------------------
template<int NR, int NS, int EPI, bool MASKED>
__global__ __launch_bounds__(512, (EPI == 0) ? 6 : 4) void edge_mfma_kernel(
    const float* __restrict__ A, const float* __restrict__ Bp,
    const float* __restrict__ W2, const float* __restrict__ b2,
    const float* __restrict__ mask,
    const float* __restrict__ Wc3, const float* __restrict__ bc3,
    float* __restrict__ out)
{
    constexpr int NE    = NR * NS;
    constexpr int NG    = NE / 48;
    constexpr int RPG   = 48 / NS;
    constexpr int PITCH = 136;
    constexpr int OP    = 132;
    constexpr int NBUF  = (EPI == 0) ? 2 : 1;
    constexpr int POUT_SZ = (EPI == 0) ? 4 : 48 * OP;
    constexpr int PART_SZ = (EPI == 2) ? 48 * 9 : 4;

    __shared__ __bf16 HVh[NBUF][48 * PITCH];
    __shared__ __bf16 HVl[NBUF][48 * PITCH];
    __shared__ float  msh[32];
    __shared__ float  POUT[POUT_SZ];
    __shared__ float  part[PART_SZ];

    const int b    = blockIdx.x;
    const int tid  = threadIdx.x;
    const int lane = tid & 63;
    const int wave = tid >> 6;
    const int lhi  = lane >> 4;
    const int llo  = lane & 15;
    const int c    = wave * 16 + llo;

    if (tid < 32) msh[tid] = (tid < NS) ? (MASKED ? mask[b * 24 + tid] : 1.f) : 0.f;

    bf16x8 bh[4], bl[4];
    {
        const float* w2c = W2 + c;
        #pragma unroll
        for (int kc = 0; kc < 4; ++kc) {
            #pragma unroll
            for (int j = 0; j < 8; ++j) {
                const float w = w2c[(size_t)(kc * 32 + lhi * 8 + j) * 128];
                const __bf16 h = (__bf16)w;
                bh[kc][j] = h;
                bl[kc][j] = (__bf16)(w - (float)h);
            }
        }
    }
    const float b2c = b2[c];
    __syncthreads();

    float inv = 1.f;
    if constexpr (EPI != 2) {
        if constexpr (MASKED) {
            float sm = 0.f;
            #pragma unroll
            for (int s = 0; s < NS; ++s) sm += msh[s];
            inv = 1.f / fmaxf(sm, 1.f);
        } else {
            inv = 1.f / (float)NS;
        }
    }

    // staged-load registers (T14: issue early, convert/write late)
    float4 ra[3], rp[3];
    auto load_regs = [&](int g) {
        #pragma unroll
        for (int it = 0; it < 3; ++it) {
            const int u = tid + it * 512;
            const int e = u >> 5, kq = u & 31;
            const int r = g * RPG + e / NS;
            const int s = e % NS;
            ra[it] = *(const float4*)(A  + ((size_t)b * NR + r) * 128 + kq * 4);
            rp[it] = *(const float4*)(Bp + ((size_t)b * NS + s) * 128 + kq * 4);
        }
    };
    auto store_buf = [&](int bi) {
        #pragma unroll
        for (int it = 0; it < 3; ++it) {
            const int u = tid + it * 512;
            const int e = u >> 5, kq = u & 31;
            const float v[4] = {fmaxf(ra[it].x + rp[it].x, 0.f), fmaxf(ra[it].y + rp[it].y, 0.f),
                                fmaxf(ra[it].z + rp[it].z, 0.f), fmaxf(ra[it].w + rp[it].w, 0.f)};
            bf16x4 hh, hl;
            #pragma unroll
            for (int q = 0; q < 4; ++q) {
                const __bf16 h = (__bf16)v[q];
                hh[q] = h;
                hl[q] = (__bf16)(v[q] - (float)h);
            }
            *(bf16x4*)&HVh[bi][e * PITCH + kq * 4] = hh;
            *(bf16x4*)&HVl[bi][e * PITCH + kq * 4] = hl;
        }
    };
    auto compute = [&](int bi, floatx4* accs) {
        #pragma unroll
        for (int mt = 0; mt < 3; ++mt) {
            const int row = mt * 16 + llo;
            floatx4 acc = {0.f, 0.f, 0.f, 0.f};
            #pragma unroll
            for (int kc = 0; kc < 4; ++kc) {
                const bf16x8 ah = *(const bf16x8*)&HVh[bi][row * PITCH + kc * 32 + lhi * 8];
                const bf16x8 al = *(const bf16x8*)&HVl[bi][row * PITCH + kc * 32 + lhi * 8];
                acc = mfma_bf16(ah, bh[kc], acc);
                acc = mfma_bf16(al, bh[kc], acc);
                acc = mfma_bf16(ah, bl[kc], acc);
            }
            accs[mt] = acc;
        }
    };

    if constexpr (EPI == 0) {
        // ---- double-buffered pipeline ----
        load_regs(0);
        store_buf(0);
        __syncthreads();
        int cur = 0;
        for (int g = 0; g < NG; ++g) {
            const bool more = (g + 1 < NG);
            if (more) load_regs(g + 1);          // issue loads; latency hides under MFMA
            floatx4 accs[3];
            compute(cur, accs);
            {   // register pooling over the 2 recv rows of this group
                float p0 = 0.f, p1 = 0.f;
                #pragma unroll
                for (int mt = 0; mt < 3; ++mt) {
                    #pragma unroll
                    for (int j = 0; j < 4; ++j) {
                        const int el = mt * 16 + lhi * 4 + j;
                        const int s  = (el >= NS) ? el - NS : el;
                        const float v = fmaxf(accs[mt][j] + b2c, 0.f) * msh[s];
                        if (el >= NS) p1 += v; else p0 += v;
                    }
                }
                p0 += __shfl_xor(p0, 16); p0 += __shfl_xor(p0, 32);
                p1 += __shfl_xor(p1, 16); p1 += __shfl_xor(p1, 32);
                if (lhi == 0) {
                    out[((size_t)b * NR + g * 2 + 0) * 128 + c] = p0 * inv;
                    out[((size_t)b * NR + g * 2 + 1) * 128 + c] = p1 * inv;
                }
            }
            if (more) store_buf(cur ^ 1);        // vmcnt wait + cvt + ds_write
            __syncthreads();
            cur ^= 1;
        }
    } else {
        // ---- single-buffered (jt / cls) ----
        for (int g = 0; g < NG; ++g) {
            load_regs(g);
            store_buf(0);
            __syncthreads();
            floatx4 accs[3];
            compute(0, accs);

            if constexpr (EPI == 1) {
                #pragma unroll
                for (int mt = 0; mt < 3; ++mt) {
                    #pragma unroll
                    for (int j = 0; j < 4; ++j) {
                        const int el = mt * 16 + lhi * 4 + j;
                        const int s  = el % NS;
                        POUT[el * OP + c] = fmaxf(accs[mt][j] + b2c, 0.f) * msh[s];
                    }
                }
                __syncthreads();
                for (int u = tid; u < RPG * 128; u += 512) {
                    const int rl = u >> 7, cc = u & 127;
                    float sm2 = 0.f;
                    #pragma unroll
                    for (int ss = 0; ss < NS; ++ss) sm2 += POUT[(rl * NS + ss) * OP + cc];
                    out[((size_t)b * NR + g * RPG + rl) * 128 + cc] = sm2 * inv;
                }
                __syncthreads();
            } else {
                #pragma unroll
                for (int mt = 0; mt < 3; ++mt) {
                    #pragma unroll
                    for (int j = 0; j < 4; ++j) {
                        const int el = mt * 16 + lhi * 4 + j;
                        POUT[el * OP + c] = fmaxf(accs[mt][j] + b2c, 0.f);
                    }
                }
                __syncthreads();
                if (tid < 384) {
                    const int e = tid >> 3, cq = tid & 7;
                    float sp = 0.f;
                    #pragma unroll
                    for (int i = 0; i < 16; ++i)
                        sp += POUT[e * OP + cq * 16 + i] * Wc3[cq * 16 + i];
                    part[e * 9 + cq] = sp;
                }
                __syncthreads();
                if (tid < 48) {
                    float sm2 = 0.f;
                    #pragma unroll
                    for (int q = 0; q < 8; ++q) sm2 += part[tid * 9 + q];
                    const int rr = g * 2 + (tid >= 24 ? 1 : 0);
                    const int ss = (tid >= 24) ? tid - 24 : tid;
                    out[((size_t)b * NR + rr) * NS + ss] =
                        msh[ss] / (1.f + expf(-(sm2 + bc3[0])));
                }
                __syncthreads();
            }
        }
    }
}

// ---------------------------------------------------------------------------
// K3: both node MLPs on MFMA.  64 rows/block, 512 threads, 8 waves.
// ---------------------------------------------------------------------------
struct NChunk { const float* base; int stride; };
struct NodeCfg {
    NChunk ch[5]; int nch;
    const __bf16* W1h; const __bf16* W1l; int w1k;
    const float* b1;
    const __bf16* W2h; const __bf16* W2l;
    const float* b2;
    const float* mask;      // per-row (B*NJ) or nullptr
    float* out;
    int nblk;
};

__global__ __launch_bounds__(512) void node_mfma_kernel(NodeCfg c0, NodeCfg c1) {
    constexpr int XP = 72;    // X pitch (bf16)
    constexpr int HP = 144;   // h1 pitch (bf16)
    __shared__ char smem[2 * 64 * HP * 2];       // 36864B; X region aliases
    __bf16* Xh  = (__bf16*)smem;                 // [64][72]
    __bf16* Xl  = Xh + 64 * XP;
    __bf16* H1h = (__bf16*)smem;                 // [64][144] (aliases X)
    __bf16* H1l = H1h + 64 * HP;

    const bool first = (int)blockIdx.x < c0.nblk;
    const NodeCfg& cfg = first ? c0 : c1;
    const int rb  = first ? blockIdx.x : blockIdx.x - c0.nblk;
    const int row0 = rb * 64;

    const int tid  = threadIdx.x;
    const int lane = tid & 63;
    const int wave = tid >> 6;
    const int lhi  = lane >> 4;
    const int llo  = lane & 15;
    const int c    = wave * 16 + llo;            // layer-1 col 0..127

    floatx4 acc[4] = {{0,0,0,0},{0,0,0,0},{0,0,0,0},{0,0,0,0}};
    for (int ch = 0; ch < cfg.nch; ++ch) {
        const NChunk cc = cfg.ch[ch];
        #pragma unroll
        for (int it = 0; it < 2; ++it) {
            const int u = tid + it * 512;
            const int r = u >> 4, kq = u & 15;
            const float4 x4 = *(const float4*)(cc.base + (size_t)(row0 + r) * cc.stride + kq * 4);
            const float v[4] = {x4.x, x4.y, x4.z, x4.w};
            bf16x4 hh, hl;
            #pragma unroll
            for (int q = 0; q < 4; ++q) {
                const __bf16 h = (__bf16)v[q];
                hh[q] = h;
                hl[q] = (__bf16)(v[q] - (float)h);
            }
            *(bf16x4*)&Xh[r * XP + kq * 4] = hh;
            *(bf16x4*)&Xl[r * XP + kq * 4] = hl;
        }
        __syncthreads();
        #pragma unroll
        for (int ks = 0; ks < 2; ++ks) {
            const int kg = ch * 64 + ks * 32 + lhi * 8;
            const bf16x8 bh = *(const bf16x8*)&cfg.W1h[(size_t)c * cfg.w1k + kg];
            const bf16x8 bl = *(const bf16x8*)&cfg.W1l[(size_t)c * cfg.w1k + kg];
            #pragma unroll
            for (int mt = 0; mt < 4; ++mt) {
                const int ro = (mt * 16 + llo) * XP + ks * 32 + lhi * 8;
                const bf16x8 ah = *(const bf16x8*)&Xh[ro];
                const bf16x8 al = *(const bf16x8*)&Xl[ro];
                acc[mt] = mfma_bf16(ah, bh, acc[mt]);
                acc[mt] = mfma_bf16(al, bh, acc[mt]);
                acc[mt] = mfma_bf16(ah, bl, acc[mt]);
            }
        }
        __syncthreads();   // X dead -> safe to overwrite (next chunk or h1)
    }

    {
        const float b1c = cfg.b1[c];
        #pragma unroll
        for (int mt = 0; mt < 4; ++mt) {
            #pragma unroll
            for (int j = 0; j < 4; ++j) {
                const int row = mt * 16 + lhi * 4 + j;
                const float v = fmaxf(acc[mt][j] + b1c, 0.f);
                const __bf16 h = (__bf16)v;
                const int blk = (c >> 3) ^ (row & 7);
                const int off = row * HP + blk * 8 + (c & 7);
                H1h[off] = h;
                H1l[off] = (__bf16)(v - (float)h);
            }
        }
    }
    __syncthreads();

    const int ct2 = wave & 3;
    const int c2  = ct2 * 16 + llo;
    const int mtb = wave >> 2;
    floatx4 acc2[2] = {{0,0,0,0},{0,0,0,0}};
    #pragma unroll
    for (int ks = 0; ks < 4; ++ks) {
        const int kg = ks * 32 + lhi * 8;
        const bf16x8 bh = *(const bf16x8*)&cfg.W2h[(size_t)c2 * 128 + kg];
        const bf16x8 bl = *(const bf16x8*)&cfg.W2l[(size_t)c2 * 128 + kg];
        #pragma unroll
        for (int i = 0; i < 2; ++i) {
            const int row = (mtb + i * 2) * 16 + llo;
            const int blk = (ks * 4 + lhi) ^ (row & 7);
            const bf16x8 ah = *(const bf16x8*)&H1h[row * HP + blk * 8];
            const bf16x8 al = *(const bf16x8*)&H1l[row * HP + blk * 8];
            acc2[i] = mfma_bf16(ah, bh, acc2[i]);
            acc2[i] = mfma_bf16(al, bh, acc2[i]);
            acc2[i] = mfma_bf16(ah, bl, acc2[i]);
        }
    }
    {
        const float b2c = cfg.b2[c2];
        #pragma unroll
        for (int i = 0; i < 2; ++i) {
            #pragma unroll
            for (int j = 0; j < 4; ++j) {
                const int row = (mtb + i * 2) * 16 + lhi * 4 + j;
                float v = fmaxf(acc2[i][j] + b2c, 0.f);
                if (cfg.mask) v *= cfg.mask[row0 + row];
                cfg.out[(size_t)(row0 + row) * 64 + c2] = v;
            }
        }
    }
}

// ---------------------------------------------------------------------------
// K6: per-top regression head (fp32): 64 -> 128 -> 128 -> 4, per-t weights.
// ---------------------------------------------------------------------------
__global__ __launch_bounds__(256) void reg_kernel(
    const float* __restrict__ tops_upd,
    const float* __restrict__ Wr1, const float* __restrict__ br1,
    const float* __restrict__ Wr2, const float* __restrict__ br2,
    const float* __restrict__ Wr3, const float* __restrict__ br3,
    float* __restrict__ outp) {
    const int t = blockIdx.y, bc = blockIdx.x, tid = threadIdx.x;
    __shared__ float Xs[32][64];
    __shared__ float h1[32][128];
    __shared__ float h2[32][132];
    __shared__ float W3s[512];
    for (int u = tid; u < 512; u += 256) {
        const int r = u >> 4, k4 = (u & 15) * 4;
        *(float4*)&Xs[r][k4] =
            *(const float4*)(tops_upd + ((size_t)(bc * 32 + r) * 6 + t) * 64 + k4);
    }
    for (int u = tid; u < 512; u += 256) W3s[u] = Wr3[t * 512 + u];
    __syncthreads();

    const int cg = tid & 31, rg = tid >> 5;
    const int c0 = cg * 4, r0 = rg * 4;
    const float* W1 = Wr1 + (size_t)t * 64 * 128;
    float4 acc[4];
    #pragma unroll
    for (int i = 0; i < 4; ++i) acc[i] = f4z();
    #pragma unroll 4
    for (int k = 0; k < 64; k += 4) {
        const float4 w0 = *(const float4*)(W1 + (size_t)(k + 0) * 128 + c0);
        const float4 w1 = *(const float4*)(W1 + (size_t)(k + 1) * 128 + c0);
        const float4 w2 = *(const float4*)(W1 + (size_t)(k + 2) * 128 + c0);
        const float4 w3 = *(const float4*)(W1 + (size_t)(k + 3) * 128 + c0);
        #pragma unroll
        for (int i = 0; i < 4; ++i) {
            const float4 x = *(const float4*)&Xs[r0 + i][k];
            acc[i] = f4fma(x.x, w0, acc[i]);
            acc[i] = f4fma(x.y, w1, acc[i]);
            acc[i] = f4fma(x.z, w2, acc[i]);
            acc[i] = f4fma(x.w, w3, acc[i]);
        }
    }
    const float4 b1v = *(const float4*)(br1 + t * 128 + c0);
    #pragma unroll
    for (int i = 0; i < 4; ++i)
        *(float4*)&h1[r0 + i][c0] = f4relu(f4add(acc[i], b1v));
    __syncthreads();

    const float* W2 = Wr2 + (size_t)t * 128 * 128;
    #pragma unroll
    for (int i = 0; i < 4; ++i) acc[i] = f4z();
    #pragma unroll 4
    for (int k = 0; k < 128; k += 4) {
        const float4 w0 = *(const float4*)(W2 + (size_t)(k + 0) * 128 + c0);
        const float4 w1 = *(const float4*)(W2 + (size_t)(k + 1) * 128 + c0);
        const float4 w2 = *(const float4*)(W2 + (size_t)(k + 2) * 128 + c0);
        const float4 w3 = *(const float4*)(W2 + (size_t)(k + 3) * 128 + c0);
        #pragma unroll
        for (int i = 0; i < 4; ++i) {
            const float4 h = *(const float4*)&h1[r0 + i][k];
            acc[i] = f4fma(h.x, w0, acc[i]);
            acc[i] = f4fma(h.y, w1, acc[i]);
            acc[i] = f4fma(h.z, w2, acc[i]);
            acc[i] = f4fma(h.w, w3, acc[i]);
        }
    }
    const float4 b2v = *(const float4*)(br2 + t * 128 + c0);
    #pragma unroll
    for (int i = 0; i < 4; ++i)
        *(float4*)&h2[r0 + i][c0] = f4relu(f4add(acc[i], b2v));
    __syncthreads();

    if (tid < 128) {
        const int r = tid >> 2, cc = tid & 3;
        float a = 0.f;
        #pragma unroll 4
        for (int k = 0; k < 128; k += 4) {
            const float4 h = *(const float4*)&h2[r][k];
            a = fmaf(h.x, W3s[(k + 0) * 4 + cc], a);
            a = fmaf(h.y, W3s[(k + 1) * 4 + cc], a);
            a = fmaf(h.z, W3s[(k + 2) * 4 + cc], a);
            a = fmaf(h.w, W3s[(k + 3) * 4 + cc], a);
        }
        outp[((size_t)(bc * 32 + r) * 6 + t) * 4 + cc] = a + br3[t * 4 + cc];
    }
}

// ---------------------------------------------------------------------------
extern "C" void kernel_launch(void* const* d_in, const int* in_sizes, int n_in,
                              void* d_out, int out_size, void* d_ws, size_t ws_size,
                              hipStream_t stream) {
    const float* jets  = (const float*)d_in[0];
    const float* mask  = (const float*)d_in[1];
    const float* tops  = (const float*)d_in[2];
    const float* W_jj1 = (const float*)d_in[3];
    const float* b_jj1 = (const float*)d_in[4];
    const float* W_jj2 = (const float*)d_in[5];
    const float* b_jj2 = (const float*)d_in[6];
    const float* W_jt1 = (const float*)d_in[7];
    const float* b_jt1 = (const float*)d_in[8];
    const float* W_jt2 = (const float*)d_in[9];
    const float* b_jt2 = (const float*)d_in[10];
    const float* W_tj1 = (const float*)d_in[11];
    const float* b_tj1 = (const float*)d_in[12];
    const float* W_tj2 = (const float*)d_in[13];
    const float* b_tj2 = (const float*)d_in[14];
    const float* Wnj1  = (const float*)d_in[15];
    const float* bnj1  = (const float*)d_in[16];
    const float* Wnj2  = (const float*)d_in[17];
    const float* bnj2  = (const float*)d_in[18];
    const float* Wnt1  = (const float*)d_in[19];
    const float* bnt1  = (const float*)d_in[20];
    const float* Wnt2  = (const float*)d_in[21];
    const float* bnt2  = (const float*)d_in[22];
    const float* Wc1   = (const float*)d_in[23];
    const float* bc1   = (const float*)d_in[24];
    const float* Wc2   = (const float*)d_in[25];
    const float* bc2   = (const float*)d_in[26];
    const float* Wc3   = (const float*)d_in[27];
    const float* bc3   = (const float*)d_in[28];
    const float* Wr1   = (const float*)d_in[29];
    const float* br1   = (const float*)d_in[30];
    const float* Wr2   = (const float*)d_in[31];
    const float* br2   = (const float*)d_in[32];
    const float* Wr3   = (const float*)d_in[33];
    const float* br3   = (const float*)d_in[34];

    float* ws = (float*)d_ws;
    constexpr size_t SZ_J = (size_t)1024 * 24 * 128;
    constexpr size_t SZ_T = (size_t)1024 * 6 * 128;
    float* Ajj = ws;
    float* Bjj = Ajj + SZ_J;
    float* Ajt = Bjj + SZ_J;
    float* Btj = Ajt + SZ_J;
    float* Atj = Btj + SZ_J;
    float* Bjt = Atj + SZ_T;
    float* Pjj = Bjt + SZ_T;
    float* Pjt = Pjj + SZ_J;
    float* Ptj = Pjt + SZ_J;
    float* Acc = Ptj + SZ_T;
    float* Bcc = Acc + SZ_T;

    // bf16 split-weight arrays alias the Acc region: Acc is written by the
    // cls pre_gemm only AFTER node_mfma has consumed these. 320KB << 3MB.
    __bf16* W1njT_h = (__bf16*)Acc;
    __bf16* W1njT_l = W1njT_h + 320 * 128;
    __bf16* W2njT_h = W1njT_l + 320 * 128;
    __bf16* W2njT_l = W2njT_h + 128 * 64;
    __bf16* W1ntT_h = W2njT_l + 128 * 64;
    __bf16* W1ntT_l = W1ntT_h + 192 * 128;
    __bf16* W2ntT_h = W1ntT_l + 192 * 128;
    __bf16* W2ntT_l = W2ntT_h + 128 * 64;

    float* outp     = (float*)d_out;
    float* upd_jets = outp;
    float* upd_tops = outp + (size_t)1024 * 24 * 64;
    float* scores   = upd_tops + (size_t)1024 * 6 * 64;
    float* regr     = scores + (size_t)1024 * 6 * 24;

    {   // weight prep (transpose + hi/lo split) for node MLPs
        PrepJobs pj;
        pj.j[0] = {Wnj1, W1njT_h, W1njT_l, 320, 128};
        pj.j[1] = {Wnj2, W2njT_h, W2njT_l, 128, 64};
        pj.j[2] = {Wnt1, W1ntT_h, W1ntT_l, 192, 128};
        pj.j[3] = {Wnt2, W2ntT_h, W2ntT_l, 128, 64};
        prep_kernel<<<dim3(160, 4), 256, 0, stream>>>(pj);
    }
    {   // per-node first-layer pre-activations for the 3 edge MLPs
        PreCfg6 cfg;
        cfg.c[0] = {jets, W_jj1,            b_jj1,  Ajj, 24576};
        cfg.c[1] = {jets, W_jj1 + 64 * 128, nullptr, Bjj, 24576};
        cfg.c[2] = {jets, W_jt1,            b_jt1,  Ajt, 24576};
        cfg.c[3] = {jets, W_tj1 + 64 * 128, nullptr, Btj, 24576};
        cfg.c[4] = {tops, W_tj1,            b_tj1,  Atj, 6144};
        cfg.c[5] = {tops, W_jt1 + 64 * 128, nullptr, Bjt, 6144};
        pre_gemm_kernel<<<dim3(768, 6), 256, 0, stream>>>(cfg);
    }
    edge_mfma_kernel<24, 24, 0, true ><<<1024, 512, 0, stream>>>(
        Ajj, Bjj, W_jj2, b_jj2, mask, nullptr, nullptr, Pjj);
    edge_mfma_kernel<24,  6, 1, false><<<1024, 512, 0, stream>>>(
        Ajt, Bjt, W_jt2, b_jt2, nullptr, nullptr, nullptr, Pjt);
    edge_mfma_kernel< 6, 24, 0, true ><<<1024, 512, 0, stream>>>(
        Atj, Btj, W_tj2, b_tj2, mask, nullptr, nullptr, Ptj);

    {   // both node MLPs, one launch
        NodeCfg cj, ct;
        cj.ch[0] = {jets, 64};
        cj.ch[1] = {Pjj, 128};      cj.ch[2] = {Pjj + 64, 128};
        cj.ch[3] = {Pjt, 128};      cj.ch[4] = {Pjt + 64, 128};
        cj.nch = 5;
        cj.W1h = W1njT_h; cj.W1l = W1njT_l; cj.w1k = 320; cj.b1 = bnj1;
        cj.W2h = W2njT_h; cj.W2l = W2njT_l; cj.b2 = bnj2;
        cj.mask = mask; cj.out = upd_jets; cj.nblk = 384;

        ct.ch[0] = {tops, 64};
        ct.ch[1] = {Ptj, 128};      ct.ch[2] = {Ptj + 64, 128};
        ct.ch[3] = {nullptr, 0};    ct.ch[4] = {nullptr, 0};
        ct.nch = 3;
        ct.W1h = W1ntT_h; ct.W1l = W1ntT_l; ct.w1k = 192; ct.b1 = bnt1;
        ct.W2h = W2ntT_h; ct.W2l = W2ntT_l; ct.b2 = bnt2;
        ct.mask = nullptr; ct.out = upd_tops; ct.nblk = 96;

        node_mfma_kernel<<<480, 512, 0, stream>>>(cj, ct);
    }

    {   // classifier-edge first layer pre-activations (overwrites Acc region)
        PreCfg6 cfg;
        cfg.c[0] = {upd_jets, Wc1 + 64 * 128, nullptr, Bcc, 24576};
        cfg.c[1] = {upd_tops, Wc1,            bc1,     Acc, 6144};
        for (int i = 2; i < 6; ++i) cfg.c[i] = {nullptr, nullptr, nullptr, nullptr, 0};
        pre_gemm_kernel<<<dim3(768, 2), 256, 0, stream>>>(cfg);
    }
    edge_mfma_kernel< 6, 24, 2, true ><<<1024, 512, 0, stream>>>(
        Acc, Bcc, Wc2, bc2, mask, Wc3, bc3, scores);
    reg_kernel<<<dim3(32, 6), 256, 0, stream>>>(upd_tops, Wr1, br1, Wr2, br2, Wr3, br3, regr);
}